// Round 2
// baseline (62.638 us; speedup 1.0000x reference)
//
#include <hip/hip_runtime.h>

// Algebraic reduction of the reference:
//   s = sum_i m_embeddings[idx[i]]           [256]
//   p = sum_i pretrained_weight[idx[i]]      [256]
//   out[c] = p[c] + dot(W[c,:], s) + N * bias[c]
//
// Kernel 1 (memory-bound): gather-sum of 2*N random 1KB rows.
//   - one wave per index batch; lane l covers channels [4l,4l+4) via float4
//   - indices preloaded per-wave (one coalesced load) and broadcast via shfl,
//     so row loads have no memory dependence -> deep pipelining
//   - 8-way replicated global accumulators to cap atomic depth at 256/addr
// Kernel 2 (negligible): sum copies, 256x256 matvec, combine.

#define NCOPY 8
#define GRID_GATHER 2048   // 8 blocks/CU on 256 CUs -> full 32 waves/CU

__global__ __launch_bounds__(256) void gather_sum_kernel(
    const int* __restrict__ idx,
    const float* __restrict__ memb,   // [VOCAB, 256]
    const float* __restrict__ pre,    // [VOCAB, 256]
    float* __restrict__ acc,          // [NCOPY][512] in d_ws
    int n)
{
    const int lane = threadIdx.x & 63;
    const int wid  = (blockIdx.x * blockDim.x + threadIdx.x) >> 6;
    const int nwaves = (GRID_GATHER * 256) >> 6;          // 8192

    // Contiguous index range for this wave (<= 64 indices: 100000/8192 ~ 13).
    const int per   = (n + nwaves - 1) / nwaves;
    const int start = wid * per;
    const int cnt   = min(per, n - start);                // may be <= 0

    // Preload this wave's indices: one coalesced load, then register-resident.
    int myidx = 0;
    if (lane < cnt) myidx = idx[start + lane];

    float4 accS = make_float4(0.f, 0.f, 0.f, 0.f);
    float4 accP = make_float4(0.f, 0.f, 0.f, 0.f);

    for (int k = 0; k < cnt; ++k) {
        const int r = __shfl(myidx, k, 64);               // broadcast, register-only dep
        const float4 a = reinterpret_cast<const float4*>(memb + (size_t)r * 256)[lane];
        const float4 b = reinterpret_cast<const float4*>(pre  + (size_t)r * 256)[lane];
        accS.x += a.x; accS.y += a.y; accS.z += a.z; accS.w += a.w;
        accP.x += b.x; accP.y += b.y; accP.z += b.z; accP.w += b.w;
    }

    // Block reduce via LDS (4 waves), then one global atomic per channel
    // into this block's accumulator copy.
    __shared__ float sS[256];
    __shared__ float sP[256];
    sS[threadIdx.x] = 0.f;
    sP[threadIdx.x] = 0.f;
    __syncthreads();

    const int c = lane * 4;
    atomicAdd(&sS[c + 0], accS.x);
    atomicAdd(&sS[c + 1], accS.y);
    atomicAdd(&sS[c + 2], accS.z);
    atomicAdd(&sS[c + 3], accS.w);
    atomicAdd(&sP[c + 0], accP.x);
    atomicAdd(&sP[c + 1], accP.y);
    atomicAdd(&sP[c + 2], accP.z);
    atomicAdd(&sP[c + 3], accP.w);
    __syncthreads();

    float* myacc = acc + (size_t)(blockIdx.x & (NCOPY - 1)) * 512;
    atomicAdd(&myacc[threadIdx.x],       sS[threadIdx.x]);
    atomicAdd(&myacc[256 + threadIdx.x], sP[threadIdx.x]);
}

__global__ __launch_bounds__(256) void finish_kernel(
    const float* __restrict__ acc,    // [NCOPY][512]
    const float* __restrict__ W,      // [256, 256] row-major: W[c][k]
    const float* __restrict__ bias,   // [256]
    float* __restrict__ out,          // [256]
    float nf)
{
    const int c = blockIdx.x;          // output channel
    const int t = threadIdx.x;         // 0..255

    float s_t = 0.f;
    #pragma unroll
    for (int cp = 0; cp < NCOPY; ++cp) s_t += acc[cp * 512 + t];

    float v = W[(size_t)c * 256 + t] * s_t;

    for (int off = 32; off > 0; off >>= 1)
        v += __shfl_down(v, off, 64);

    __shared__ float part[4];
    if ((t & 63) == 0) part[t >> 6] = v;
    __syncthreads();

    if (t == 0) {
        float p_c = 0.f;
        #pragma unroll
        for (int cp = 0; cp < NCOPY; ++cp) p_c += acc[cp * 512 + 256 + c];
        out[c] = (part[0] + part[1] + part[2] + part[3]) + p_c + nf * bias[c];
    }
}

extern "C" void kernel_launch(void* const* d_in, const int* in_sizes, int n_in,
                              void* d_out, int out_size, void* d_ws, size_t ws_size,
                              hipStream_t stream)
{
    const int*   idx  = (const int*)d_in[0];     // medicine_it      [N]
    const float* memb = (const float*)d_in[1];   // m_embeddings     [VOCAB,256]
    const float* pre  = (const float*)d_in[2];   // pretrained_weight[VOCAB,256]
    const float* W    = (const float*)d_in[3];   // W                [256,256]
    const float* bias = (const float*)d_in[4];   // bias             [256]
    float* out = (float*)d_out;                  // [1,1,256] -> 256 floats

    const int n = in_sizes[0];

    float* acc = (float*)d_ws;                   // [NCOPY][512]

    hipMemsetAsync(d_ws, 0, NCOPY * 512 * sizeof(float), stream);

    gather_sum_kernel<<<GRID_GATHER, 256, 0, stream>>>(idx, memb, pre, acc, n);
    finish_kernel<<<256, 256, 0, stream>>>(acc, W, bias, out, (float)n);
}

// Round 3
// 53.891 us; speedup vs baseline: 1.1623x; 1.1623x over previous
//
#include <hip/hip_runtime.h>

// out[c] = sum_i pre[idx_i][c] + dot(W[c,:], sum_i memb[idx_i]) + N*bias[c]
//
// Histogram formulation: only ~39% of vocab rows are touched
// (N=100k uniform draws over V=200k). counts[v] = multiplicity, then a
// monotone weighted scan over rows with count>0 reads each unique row ONCE:
//   s = sum_v counts[v]*memb[v],  p = sum_v counts[v]*pre[v]
// ~162 MB instead of ~205 MB, in increasing-address order.
//
// d_ws layout: [counts: V int32][acc: NCOPY*512 float]

#define NCOPY 16

__device__ inline void fma4(float4& acc, float w, const float4& v) {
    acc.x = fmaf(w, v.x, acc.x);
    acc.y = fmaf(w, v.y, acc.y);
    acc.z = fmaf(w, v.z, acc.z);
    acc.w = fmaf(w, v.w, acc.w);
}

__global__ __launch_bounds__(256) void hist_kernel(
    const int* __restrict__ idx, int* __restrict__ counts, int n)
{
    int i = blockIdx.x * blockDim.x + threadIdx.x;
    const int stride = gridDim.x * blockDim.x;
    for (; i < n; i += stride) atomicAdd(&counts[idx[i]], 1);
}

__global__ __launch_bounds__(256) void scan_kernel(
    const int* __restrict__ counts,
    const float* __restrict__ memb,   // [V,256]
    const float* __restrict__ pre,    // [V,256]
    float* __restrict__ acc,          // [NCOPY][512]
    int vocab)
{
    const int lane = threadIdx.x & 63;
    const int wid  = (blockIdx.x * blockDim.x + threadIdx.x) >> 6;
    const int base = wid * 64;                 // 64 consecutive rows per wave

    float4 accS = make_float4(0.f, 0.f, 0.f, 0.f);
    float4 accP = make_float4(0.f, 0.f, 0.f, 0.f);

    if (base < vocab) {
        int c = 0;
        if (base + lane < vocab) c = counts[base + lane];   // coalesced
        const float cf = (float)c;
        unsigned long long m = __ballot(c != 0);

        // Process surviving rows two at a time (more loads in flight).
        while (m) {
            const int k1 = __ffsll(m) - 1;  m &= m - 1;
            const float w1 = __shfl(cf, k1, 64);
            const float4 a1 = reinterpret_cast<const float4*>(memb + (size_t)(base + k1) * 256)[lane];
            const float4 b1 = reinterpret_cast<const float4*>(pre  + (size_t)(base + k1) * 256)[lane];
            if (m) {
                const int k2 = __ffsll(m) - 1;  m &= m - 1;
                const float w2 = __shfl(cf, k2, 64);
                const float4 a2 = reinterpret_cast<const float4*>(memb + (size_t)(base + k2) * 256)[lane];
                const float4 b2 = reinterpret_cast<const float4*>(pre  + (size_t)(base + k2) * 256)[lane];
                fma4(accS, w1, a1); fma4(accP, w1, b1);
                fma4(accS, w2, a2); fma4(accP, w2, b2);
            } else {
                fma4(accS, w1, a1); fma4(accP, w1, b1);
            }
        }
    }

    // Block reduce (lane l owns channels [4l,4l+4)) then one global atomic
    // per channel into this block's accumulator copy.
    __shared__ float sS[256];
    __shared__ float sP[256];
    sS[threadIdx.x] = 0.f;
    sP[threadIdx.x] = 0.f;
    __syncthreads();

    const int ch = lane * 4;
    atomicAdd(&sS[ch + 0], accS.x); atomicAdd(&sS[ch + 1], accS.y);
    atomicAdd(&sS[ch + 2], accS.z); atomicAdd(&sS[ch + 3], accS.w);
    atomicAdd(&sP[ch + 0], accP.x); atomicAdd(&sP[ch + 1], accP.y);
    atomicAdd(&sP[ch + 2], accP.z); atomicAdd(&sP[ch + 3], accP.w);
    __syncthreads();

    float* myacc = acc + (size_t)(blockIdx.x & (NCOPY - 1)) * 512;
    atomicAdd(&myacc[threadIdx.x],       sS[threadIdx.x]);
    atomicAdd(&myacc[256 + threadIdx.x], sP[threadIdx.x]);
}

// Fallback (small ws): direct strided gather like R1, into acc copies.
__global__ __launch_bounds__(256) void gather_sum_kernel(
    const int* __restrict__ idx,
    const float* __restrict__ memb,
    const float* __restrict__ pre,
    float* __restrict__ acc,
    int n)
{
    const int lane = threadIdx.x & 63;
    const int wave = threadIdx.x >> 6;
    const int globalWave = blockIdx.x * 4 + wave;
    const int totalWaves = gridDim.x * 4;

    float4 accS = make_float4(0.f, 0.f, 0.f, 0.f);
    float4 accP = make_float4(0.f, 0.f, 0.f, 0.f);

    for (int i = globalWave; i < n; i += totalWaves) {
        const int r = idx[i];
        const float4 a = reinterpret_cast<const float4*>(memb + (size_t)r * 256)[lane];
        const float4 b = reinterpret_cast<const float4*>(pre  + (size_t)r * 256)[lane];
        accS.x += a.x; accS.y += a.y; accS.z += a.z; accS.w += a.w;
        accP.x += b.x; accP.y += b.y; accP.z += b.z; accP.w += b.w;
    }

    __shared__ float sS[256];
    __shared__ float sP[256];
    sS[threadIdx.x] = 0.f;
    sP[threadIdx.x] = 0.f;
    __syncthreads();
    const int ch = lane * 4;
    atomicAdd(&sS[ch + 0], accS.x); atomicAdd(&sS[ch + 1], accS.y);
    atomicAdd(&sS[ch + 2], accS.z); atomicAdd(&sS[ch + 3], accS.w);
    atomicAdd(&sP[ch + 0], accP.x); atomicAdd(&sP[ch + 1], accP.y);
    atomicAdd(&sP[ch + 2], accP.z); atomicAdd(&sP[ch + 3], accP.w);
    __syncthreads();
    float* myacc = acc + (size_t)(blockIdx.x & (NCOPY - 1)) * 512;
    atomicAdd(&myacc[threadIdx.x],       sS[threadIdx.x]);
    atomicAdd(&myacc[256 + threadIdx.x], sP[threadIdx.x]);
}

__global__ __launch_bounds__(256) void finish_kernel(
    const float* __restrict__ acc,    // [NCOPY][512]
    const float* __restrict__ W,      // [256,256] row-major
    const float* __restrict__ bias,
    float* __restrict__ out,          // [256]
    float nf)
{
    const int c = blockIdx.x;
    const int t = threadIdx.x;

    float s_t = 0.f;
    #pragma unroll
    for (int cp = 0; cp < NCOPY; ++cp) s_t += acc[cp * 512 + t];

    float v = W[(size_t)c * 256 + t] * s_t;
    for (int off = 32; off > 0; off >>= 1)
        v += __shfl_down(v, off, 64);

    __shared__ float part[4];
    if ((t & 63) == 0) part[t >> 6] = v;
    __syncthreads();

    if (t == 0) {
        float p_c = 0.f;
        #pragma unroll
        for (int cp = 0; cp < NCOPY; ++cp) p_c += acc[cp * 512 + 256 + c];
        out[c] = (part[0] + part[1] + part[2] + part[3]) + p_c + nf * bias[c];
    }
}

extern "C" void kernel_launch(void* const* d_in, const int* in_sizes, int n_in,
                              void* d_out, int out_size, void* d_ws, size_t ws_size,
                              hipStream_t stream)
{
    const int*   idx  = (const int*)d_in[0];     // medicine_it      [N]
    const float* memb = (const float*)d_in[1];   // m_embeddings     [V,256]
    const float* pre  = (const float*)d_in[2];   // pretrained_weight[V,256]
    const float* W    = (const float*)d_in[3];   // W                [256,256]
    const float* bias = (const float*)d_in[4];   // bias             [256]
    float* out = (float*)d_out;

    const int n     = in_sizes[0];
    const int vocab = in_sizes[1] / 256;

    const size_t countsBytes = (size_t)vocab * sizeof(int);
    const size_t accBytes    = (size_t)NCOPY * 512 * sizeof(float);

    if (ws_size >= countsBytes + accBytes) {
        int*   counts = (int*)d_ws;
        float* acc    = (float*)((char*)d_ws + countsBytes);

        hipMemsetAsync(d_ws, 0, countsBytes + accBytes, stream);
        hist_kernel<<<400, 256, 0, stream>>>(idx, counts, n);

        const int waves  = (vocab + 63) / 64;
        const int blocks = (waves + 3) / 4;
        scan_kernel<<<blocks, 256, 0, stream>>>(counts, memb, pre, acc, vocab);
        finish_kernel<<<256, 256, 0, stream>>>(acc, W, bias, out, (float)n);
    } else {
        float* acc = (float*)d_ws;
        hipMemsetAsync(d_ws, 0, accBytes, stream);
        gather_sum_kernel<<<512, 256, 0, stream>>>(idx, memb, pre, acc, n);
        finish_kernel<<<256, 256, 0, stream>>>(acc, W, bias, out, (float)n);
    }
}